// Round 11
// baseline (715.185 us; speedup 1.0000x reference)
//
#include <hip/hip_runtime.h>
#include <hip/hip_fp16.h>

#define D 128

typedef _Float16 half8 __attribute__((ext_vector_type(8)));
typedef float floatx4 __attribute__((ext_vector_type(4)));

// ---------------- helpers ----------------

// fused f16->f32 convert + FMA (pattern-matches v_fma_mix_f32)
__device__ inline void acc_h4(float& ax, float& ay, float& az, float& aw,
                              float w, uint2 raw) {
    __half2 h01 = *reinterpret_cast<const __half2*>(&raw.x);
    __half2 h23 = *reinterpret_cast<const __half2*>(&raw.y);
    ax = fmaf(w, __low2float(h01), ax);
    ay = fmaf(w, __high2float(h01), ay);
    az = fmaf(w, __low2float(h23), az);
    aw = fmaf(w, __high2float(h23), aw);
}

// ---------------- setup kernels ----------------

__global__ void k_zero(int* __restrict__ p, int n) {
    int i = blockIdx.x * 256 + threadIdx.x;
    if (i < n) p[i] = 0;
}

// count degrees AND record each edge's rank within its destination
__global__ void k_count(const int* __restrict__ dst, int* __restrict__ cnt,
                        int* __restrict__ rank, int e) {
    int i = blockIdx.x * 256 + threadIdx.x;
    if (i < e) rank[i] = atomicAdd(&cnt[dst[i]], 1);
}

// f32 -> fp16 streaming convert (8 elems/thread), row-major
__global__ void k_f2h(const float* __restrict__ in, __half* __restrict__ out, int n8) {
    int i = blockIdx.x * 256 + threadIdx.x;
    if (i < n8) {
        const float4* p = (const float4*)in + (size_t)i * 2;
        float4 a = p[0], b = p[1];
        __half2 h0 = __float22half2_rn(make_float2(a.x, a.y));
        __half2 h1 = __float22half2_rn(make_float2(a.z, a.w));
        __half2 h2 = __float22half2_rn(make_float2(b.x, b.y));
        __half2 h3 = __float22half2_rn(make_float2(b.z, b.w));
        uint4 o;
        o.x = *(unsigned*)&h0; o.y = *(unsigned*)&h1;
        o.z = *(unsigned*)&h2; o.w = *(unsigned*)&h3;
        ((uint4*)out)[i] = o;
    }
}

// ---- hierarchical scan (+ fused dinv) ----

__global__ __launch_bounds__(256) void k_scanA(const int* __restrict__ cnt,
                                               int* __restrict__ partials,
                                               float* __restrict__ dinv, int n) {
    __shared__ int s[256];
    int b = blockIdx.x, t = threadIdx.x;
    int i0 = b * 512 + t * 2;
    int v = 0;
    if (i0 < n) {
        int c0 = cnt[i0];
        v += c0;
        dinv[i0] = 1.0f / sqrtf((float)(c0 + 2));
    }
    if (i0 + 1 < n) {
        int c1 = cnt[i0 + 1];
        v += c1;
        dinv[i0 + 1] = 1.0f / sqrtf((float)(c1 + 2));
    }
    s[t] = v;
    __syncthreads();
    for (int off = 128; off > 0; off >>= 1) {
        if (t < off) s[t] += s[t + off];
        __syncthreads();
    }
    if (t == 0) partials[b] = s[0];
}

__global__ __launch_bounds__(512) void k_scanB(const int* __restrict__ partials,
                                               int* __restrict__ base,
                                               int* __restrict__ off_n, int nb) {
    __shared__ int s[512];
    int t = threadIdx.x;
    int v = (t < nb) ? partials[t] : 0;
    s[t] = v;
    __syncthreads();
    for (int off = 1; off < 512; off <<= 1) {
        int x = (t >= off) ? s[t - off] : 0;
        __syncthreads();
        s[t] += x;
        __syncthreads();
    }
    if (t < nb) base[t] = s[t] - v;          // exclusive
    if (t == nb - 1) off_n[0] = s[t];        // total = offsets[N]
}

__global__ __launch_bounds__(256) void k_scanC(const int* __restrict__ cnt,
                                               const int* __restrict__ base,
                                               int* __restrict__ offsets, int n) {
    __shared__ int s[256];
    int b = blockIdx.x, t = threadIdx.x;
    int i0 = b * 512 + t * 2;
    int v0 = (i0 < n) ? cnt[i0] : 0;
    int v1 = (i0 + 1 < n) ? cnt[i0 + 1] : 0;
    int sum = v0 + v1;
    s[t] = sum;
    __syncthreads();
    for (int off = 1; off < 256; off <<= 1) {
        int x = (t >= off) ? s[t - off] : 0;
        __syncthreads();
        s[t] += x;
        __syncthreads();
    }
    int excl = s[t] - sum + base[b];
    if (i0 < n) offsets[i0] = excl;
    if (i0 + 1 < n) offsets[i0 + 1] = excl + v0;
}

// packed CSR entry: .x = src, .y = bit-cast float norm; slot = offsets[dst]+rank
__global__ void k_fill(const int* __restrict__ src, const int* __restrict__ dst,
                       const int* __restrict__ rank, const int* __restrict__ offsets,
                       const float* __restrict__ dinv, int2* __restrict__ csr, int e) {
    int i = blockIdx.x * 256 + threadIdx.x;
    if (i < e) {
        int s = src[i];
        int d = dst[i];
        int pos = offsets[d] + rank[i];
        csr[pos] = make_int2(s, __float_as_int(dinv[s] * dinv[d]));
    }
}

// small 128x128 @ 128x128
__global__ __launch_bounds__(128) void k_wmm(const float* __restrict__ A,
                                             const float* __restrict__ B,
                                             float* __restrict__ Cm) {
    __shared__ float a[128];
    int r = blockIdx.x, d = threadIdx.x;
    a[d] = A[r * 128 + d];
    __syncthreads();
    float acc = 0.0f;
#pragma unroll 8
    for (int k = 0; k < 128; k++) acc += a[k] * B[k * 128 + d];
    Cm[r * 128 + d] = acc;
}

// blocks 0..127: row r of Wtot = W1 @ W4, written DIRECTLY as hi/lo MFMA
// B-fragments into pack. frag(s,t): lane l, elem j holds
// W[s*32 + 8*(l>>4) + j][t*16 + (l&15)];
// inverse for (R,C): s=R>>5, j=R&7, l=((R>>3)&3)*16+(C&15), t=C>>4.
// block 128: bias chain -> cmat rows 0..3 = b2 W2^j, row 4 = b1 W4.
__global__ __launch_bounds__(128) void k_wmm_bias(const float* __restrict__ W1,
                                                  const float* __restrict__ W4,
                                                  const float* __restrict__ W2,
                                                  const float* __restrict__ b1,
                                                  const float* __restrict__ b2,
                                                  __half* __restrict__ pack,
                                                  float* __restrict__ cmat) {
    __shared__ float s[128];
    int d = threadIdx.x;
    if (blockIdx.x < 128) {
        int r = blockIdx.x;
        s[d] = W1[r * 128 + d];
        __syncthreads();
        float acc = 0.0f;
#pragma unroll 8
        for (int k = 0; k < 128; k++) acc += s[k] * W4[k * 128 + d];
        // pack slot for element (r, d)
        int ss = r >> 5, j = r & 7;
        int l = ((r >> 3) & 3) * 16 + (d & 15);
        int t = d >> 4;
        int tid = ss * 512 + t * 64 + l;
        __half hh = __float2half(acc);
        float rem = acc - __half2float(hh);
        pack[(size_t)tid * 8 + j] = hh;
        pack[16384 + (size_t)tid * 8 + j] = __float2half(rem);
        return;
    }
    float v = b2[d];
    cmat[d] = v;
    for (int j = 1; j <= 3; j++) {
        s[d] = v;
        __syncthreads();
        float acc = 0.0f;
#pragma unroll 8
        for (int k = 0; k < 128; k++) acc += s[k] * W2[k * 128 + d];
        v = acc;
        cmat[j * 128 + d] = v;
        __syncthreads();
    }
    s[d] = b1[d];
    __syncthreads();
    float acc = 0.0f;
#pragma unroll 8
    for (int k = 0; k < 128; k++) acc += s[k] * W4[k * 128 + d];
    cmat[4 * 128 + d] = acc;
}

// ---------------- gather: O = A T (+ optional fused u_out = A u_in) --------
// Row-major fp16 rows (256B): half-wave per row = 32 lanes x 8B; 8-edge main
// loop = 4 independent dual-row loads in flight (measured-optimal geometry).
template <bool WITH_U, bool IN_F16>
__global__ __launch_bounds__(256) void k_gather(const void* __restrict__ Tv,
                                                const int2* __restrict__ csr,
                                                const int* __restrict__ offsets,
                                                const float* __restrict__ dinv,
                                                __half* __restrict__ Ov,
                                                const float* __restrict__ uin,
                                                float* __restrict__ uout, int n) {
    int node = blockIdx.x * 4 + (threadIdx.x >> 6);
    if (node >= n) return;
    int lane = threadIdx.x & 63;
    int hf = lane >> 5;              // 0 or 1
    int c = (lane & 31) << 2;        // col base (4 cols)
    const __half* Tch = (const __half*)Tv + c;
    const float*  Tcf = (const float*)Tv + c;

    float ax = 0.f, ay = 0.f, az = 0.f, aw = 0.f;
    float uacc = 0.f;
    if (hf == 0) {
        float di = dinv[node];
        float sw = 2.0f * di * di;
        if (IN_F16) {
            uint2 raw = *(const uint2*)(Tch + (size_t)node * D);
            acc_h4(ax, ay, az, aw, sw, raw);
        } else {
            float4 v = *(const float4*)(Tcf + (size_t)node * D);
            ax = sw * v.x; ay = sw * v.y; az = sw * v.z; aw = sw * v.w;
        }
        if (WITH_U) uacc = sw * (uin ? uin[node] : 1.0f);
    }

    int e = offsets[node];
    const int e1 = offsets[node + 1];

    for (; e + 8 <= e1; e += 8) {
        int2 p0 = csr[e + hf];
        int2 p1 = csr[e + 2 + hf];
        int2 p2 = csr[e + 4 + hf];
        int2 p3 = csr[e + 6 + hf];
        float w0 = __int_as_float(p0.y), w1 = __int_as_float(p1.y);
        float w2 = __int_as_float(p2.y), w3 = __int_as_float(p3.y);
        if (IN_F16) {
            uint2 r0 = *(const uint2*)(Tch + (size_t)p0.x * D);
            uint2 r1 = *(const uint2*)(Tch + (size_t)p1.x * D);
            uint2 r2 = *(const uint2*)(Tch + (size_t)p2.x * D);
            uint2 r3 = *(const uint2*)(Tch + (size_t)p3.x * D);
            if (WITH_U) {
                if (uin) {
                    uacc += w0 * uin[p0.x] + w1 * uin[p1.x]
                          + w2 * uin[p2.x] + w3 * uin[p3.x];
                } else {
                    uacc += w0 + w1 + w2 + w3;
                }
            }
            acc_h4(ax, ay, az, aw, w0, r0);
            acc_h4(ax, ay, az, aw, w1, r1);
            acc_h4(ax, ay, az, aw, w2, r2);
            acc_h4(ax, ay, az, aw, w3, r3);
        } else {
            float4 v0 = *(const float4*)(Tcf + (size_t)p0.x * D);
            float4 v1 = *(const float4*)(Tcf + (size_t)p1.x * D);
            float4 v2 = *(const float4*)(Tcf + (size_t)p2.x * D);
            float4 v3 = *(const float4*)(Tcf + (size_t)p3.x * D);
            if (WITH_U) {
                if (uin) {
                    uacc += w0 * uin[p0.x] + w1 * uin[p1.x]
                          + w2 * uin[p2.x] + w3 * uin[p3.x];
                } else {
                    uacc += w0 + w1 + w2 + w3;
                }
            }
            ax += w0 * v0.x; ay += w0 * v0.y; az += w0 * v0.z; aw += w0 * v0.w;
            ax += w1 * v1.x; ay += w1 * v1.y; az += w1 * v1.z; aw += w1 * v1.w;
            ax += w2 * v2.x; ay += w2 * v2.y; az += w2 * v2.z; aw += w2 * v2.w;
            ax += w3 * v3.x; ay += w3 * v3.y; az += w3 * v3.z; aw += w3 * v3.w;
        }
    }
    for (; e + 2 <= e1; e += 2) {
        int2 p0 = csr[e + hf];
        float w0 = __int_as_float(p0.y);
        if (WITH_U) uacc += w0 * (uin ? uin[p0.x] : 1.0f);
        if (IN_F16) {
            uint2 r0 = *(const uint2*)(Tch + (size_t)p0.x * D);
            acc_h4(ax, ay, az, aw, w0, r0);
        } else {
            float4 v0 = *(const float4*)(Tcf + (size_t)p0.x * D);
            ax += w0 * v0.x; ay += w0 * v0.y; az += w0 * v0.z; aw += w0 * v0.w;
        }
    }
    if (e < e1 && hf == 0) {
        int2 p0 = csr[e];
        float w0 = __int_as_float(p0.y);
        if (WITH_U) uacc += w0 * (uin ? uin[p0.x] : 1.0f);
        if (IN_F16) {
            uint2 r0 = *(const uint2*)(Tch + (size_t)p0.x * D);
            acc_h4(ax, ay, az, aw, w0, r0);
        } else {
            float4 v0 = *(const float4*)(Tcf + (size_t)p0.x * D);
            ax += w0 * v0.x; ay += w0 * v0.y; az += w0 * v0.z; aw += w0 * v0.w;
        }
    }

    ax += __shfl_xor(ax, 32, 64);
    ay += __shfl_xor(ay, 32, 64);
    az += __shfl_xor(az, 32, 64);
    aw += __shfl_xor(aw, 32, 64);
    if (WITH_U) uacc += __shfl_xor(uacc, 32, 64);

    if (hf == 0) {
        __half2 o01 = __float22half2_rn(make_float2(ax, ay));
        __half2 o23 = __float22half2_rn(make_float2(az, aw));
        float2 raw;
        *(__half2*)&raw.x = o01;
        *(__half2*)&raw.y = o23;
        *(float2*)(Ov + (size_t)node * D + c) = raw;
        if (WITH_U && lane == 0) uout[node] = uacc;
    }
}

// ---------- fused gather-5 + matmul: O = (A T) @ Wtot + b2 + U C ----------
// Gather phase: EXACT k_gather geometry (1 node/wave, 4 nodes/block), fp16
// result -> 1KB LDS instead of global (saves T16 write + matmul re-read,
// ~51MB). MFMA phase: per block, 4 valid A-rows zero-padded to the 16x16
// tile; wave w computes col-tiles 2w, 2w+1 (16 MFMA/wave — issue-free).
// Numerically identical to gather->matmul (same fp16 rounding point).
__global__ __launch_bounds__(256) void k_gather_mm(const __half* __restrict__ Tv,
                                                   const int2* __restrict__ csr,
                                                   const int* __restrict__ offsets,
                                                   const float* __restrict__ dinv,
                                                   const __half* __restrict__ Wpack,
                                                   float* __restrict__ O,
                                                   const float* __restrict__ ucol,
                                                   const float* __restrict__ cmat,
                                                   int n) {
    __shared__ __half rows[4][128];
    const int wave = threadIdx.x >> 6;
    const int lane = threadIdx.x & 63;
    const int node0 = blockIdx.x * 4;
    const int node = node0 + wave;
    const bool active = node < n;

    // ---- gather phase ----
    const int hf = lane >> 5;
    const int c = (lane & 31) << 2;
    const __half* Tch = Tv + c;

    float ax = 0.f, ay = 0.f, az = 0.f, aw = 0.f;
    if (active) {
        if (hf == 0) {
            float di = dinv[node];
            float sw = 2.0f * di * di;
            uint2 raw = *(const uint2*)(Tch + (size_t)node * D);
            acc_h4(ax, ay, az, aw, sw, raw);
        }
        int e = offsets[node];
        const int e1 = offsets[node + 1];
        for (; e + 8 <= e1; e += 8) {
            int2 p0 = csr[e + hf];
            int2 p1 = csr[e + 2 + hf];
            int2 p2 = csr[e + 4 + hf];
            int2 p3 = csr[e + 6 + hf];
            float w0 = __int_as_float(p0.y), w1 = __int_as_float(p1.y);
            float w2 = __int_as_float(p2.y), w3 = __int_as_float(p3.y);
            uint2 r0 = *(const uint2*)(Tch + (size_t)p0.x * D);
            uint2 r1 = *(const uint2*)(Tch + (size_t)p1.x * D);
            uint2 r2 = *(const uint2*)(Tch + (size_t)p2.x * D);
            uint2 r3 = *(const uint2*)(Tch + (size_t)p3.x * D);
            acc_h4(ax, ay, az, aw, w0, r0);
            acc_h4(ax, ay, az, aw, w1, r1);
            acc_h4(ax, ay, az, aw, w2, r2);
            acc_h4(ax, ay, az, aw, w3, r3);
        }
        for (; e + 2 <= e1; e += 2) {
            int2 p0 = csr[e + hf];
            float w0 = __int_as_float(p0.y);
            uint2 r0 = *(const uint2*)(Tch + (size_t)p0.x * D);
            acc_h4(ax, ay, az, aw, w0, r0);
        }
        if (e < e1 && hf == 0) {
            int2 p0 = csr[e];
            float w0 = __int_as_float(p0.y);
            uint2 r0 = *(const uint2*)(Tch + (size_t)p0.x * D);
            acc_h4(ax, ay, az, aw, w0, r0);
        }
        ax += __shfl_xor(ax, 32, 64);
        ay += __shfl_xor(ay, 32, 64);
        az += __shfl_xor(az, 32, 64);
        aw += __shfl_xor(aw, 32, 64);
    }
    if (hf == 0) {
        __half2 o01 = __float22half2_rn(make_float2(ax, ay));
        __half2 o23 = __float22half2_rn(make_float2(az, aw));
        float2 raw;
        *(__half2*)&raw.x = o01;
        *(__half2*)&raw.y = o23;
        if (!active) raw = make_float2(0.f, 0.f);   // zero pad rows
        *(float2*)(&rows[wave][c]) = raw;
    }
    __syncthreads();

    // ---- MFMA phase: wave handles col-tiles 2*wave, 2*wave+1 ----
    const int lrow = lane & 15, lk = lane >> 4;
    const int t0 = 2 * wave;

    floatx4 acc[2];
#pragma unroll
    for (int ti = 0; ti < 2; ti++) {
        int col = (t0 + ti) * 16 + lrow;
        float c0 = cmat[col];
        float c1 = cmat[128 + col], c2 = cmat[256 + col];
        float c3 = cmat[384 + col], c4 = cmat[512 + col];
#pragma unroll
        for (int r = 0; r < 4; r++) {
            int rowN = node0 + lk * 4 + r;     // only lk==0 rows are stored
            float v = c0;
            if (lk == 0 && rowN < n) {
                v += ucol[(size_t)0 * n + rowN] * c1
                   + ucol[(size_t)1 * n + rowN] * c2
                   + ucol[(size_t)2 * n + rowN] * c3
                   + ucol[(size_t)3 * n + rowN] * c4;
            }
            acc[ti][r] = v;
        }
    }

#pragma unroll
    for (int s = 0; s < 4; s++) {
        half8 a;
        if (lrow < 4) {
            a = *reinterpret_cast<const half8*>(&rows[lrow][s * 32 + lk * 8]);
        } else {
            a = half8{0, 0, 0, 0, 0, 0, 0, 0};
        }
        const __half* wb = Wpack + (size_t)s * 4096 + (size_t)lane * 8;
#pragma unroll
        for (int ti = 0; ti < 2; ti++) {
            half8 bh = *reinterpret_cast<const half8*>(wb + (size_t)(t0 + ti) * 512);
            half8 bl = *reinterpret_cast<const half8*>(wb + (size_t)(t0 + ti) * 512 + 16384);
            acc[ti] = __builtin_amdgcn_mfma_f32_16x16x32_f16(a, bh, acc[ti], 0, 0, 0);
            acc[ti] = __builtin_amdgcn_mfma_f32_16x16x32_f16(a, bl, acc[ti], 0, 0, 0);
        }
    }

    // C/D layout: col = lane&15, row = lk*4 + reg; valid A rows are 0..3 (lk==0)
    if (lk == 0) {
#pragma unroll
        for (int r = 0; r < 4; r++) {
            int rowN = node0 + r;
            if (rowN < n) {
#pragma unroll
                for (int ti = 0; ti < 2; ti++)
                    O[(size_t)rowN * 128 + (t0 + ti) * 16 + lrow] = acc[ti][r];
            }
        }
    }
}

// ---------------- launch ----------------
// out = (A^5 x)(W1 W2^4) + b2 + sum_{j=1..3}(A^j 1)(b2 W2^j) + (A^4 1)(b1 W2^4)
// Intermediates fp16 row-major (f32 accumulate); gather-5 fused with the
// MFMA matmul (W hi/lo split).

extern "C" void kernel_launch(void* const* d_in, const int* in_sizes, int n_in,
                              void* d_out, int out_size, void* d_ws, size_t ws_size,
                              hipStream_t stream) {
    const float* x  = (const float*)d_in[0];
    const int*   ei = (const int*)d_in[1];
    const float* W1 = (const float*)d_in[2];
    const float* b1 = (const float*)d_in[3];
    const float* W2 = (const float*)d_in[4];
    const float* b2 = (const float*)d_in[5];
    const int N = in_sizes[0] / D;
    const int E = in_sizes[1] / 2;
    float* out = (float*)d_out;

    char* ws = (char*)d_ws;
    size_t woff = 0;
    auto alloc = [&](size_t bytes) -> void* {
        void* p = ws + woff;
        woff = (woff + bytes + 15) & ~(size_t)15;
        return p;
    };
    __half* T16a    = (__half*)alloc((size_t)N * D * sizeof(__half));
    __half* T16b    = (__half*)alloc((size_t)N * D * sizeof(__half));
    int*   cnt      = (int*)  alloc((size_t)N * sizeof(int));
    int*   offsets  = (int*)  alloc((size_t)(N + 1) * sizeof(int));
    int*   rank     = (int*)  alloc((size_t)E * sizeof(int));
    float* dinv     = (float*)alloc((size_t)N * sizeof(float));
    int2*  csr      = (int2*) alloc((size_t)E * sizeof(int2));
    int*   partials = (int*)  alloc(1024 * sizeof(int));
    int*   base     = (int*)  alloc(1024 * sizeof(int));
    float* ucol     = (float*)alloc((size_t)4 * N * sizeof(float));   // [4][N]
    float* cmat     = (float*)alloc(5 * 128 * sizeof(float));         // [5][128]
    float* Wsq      = (float*)alloc(128 * 128 * sizeof(float));
    float* W4       = (float*)alloc(128 * 128 * sizeof(float));
    __half* Wpack   = (__half*)alloc(32768 * sizeof(__half));         // hi|lo frags
    size_t x16_bytes = (size_t)N * D * sizeof(__half);
    bool use_x16 = (woff + x16_bytes) <= ws_size;
    __half* X16 = use_x16 ? (__half*)alloc(x16_bytes) : nullptr;
    (void)n_in; (void)out_size;

    const int* e_src = ei;
    const int* e_dst = ei + E;
    const int NB = (N + 511) / 512;

    // --- weight chain first (independent): Wsq = W2^2, W4 = W2^4,
    //     [Wtot = W1 W4 -> packed hi/lo MFMA frags || bias chain] ---
    k_wmm<<<128, 128, 0, stream>>>(W2, W2, Wsq);
    k_wmm<<<128, 128, 0, stream>>>(Wsq, Wsq, W4);
    k_wmm_bias<<<129, 128, 0, stream>>>(W1, W4, W2, b1, b2, Wpack, cmat);

    // --- CSR build (rank-based, no atomic in fill) ---
    k_zero<<<(N + 255) / 256, 256, 0, stream>>>(cnt, N);
    k_count<<<(E + 255) / 256, 256, 0, stream>>>(e_dst, cnt, rank, E);
    k_scanA<<<NB, 256, 0, stream>>>(cnt, partials, dinv, N);
    k_scanB<<<1, 512, 0, stream>>>(partials, base, offsets + N, NB);
    k_scanC<<<NB, 256, 0, stream>>>(cnt, base, offsets, N);
    k_fill<<<(E + 255) / 256, 256, 0, stream>>>(e_src, e_dst, rank, offsets,
                                                dinv, csr, E);

    // --- g = A^5 x (fp16 ping-pong); u_j = A^j 1 fused into gathers 1-4;
    //     gather-5 fused with the dense matmul ---
    const int GG = (N + 3) / 4;
    if (use_x16) {
        int n8 = (N * D) / 8;
        k_f2h<<<(n8 + 255) / 256, 256, 0, stream>>>(x, X16, n8);
        k_gather<true, true><<<GG, 256, 0, stream>>>(
            X16, csr, offsets, dinv, T16a, nullptr, ucol, N);
    } else {
        k_gather<true, false><<<GG, 256, 0, stream>>>(
            x, csr, offsets, dinv, T16a, nullptr, ucol, N);
    }
    k_gather<true, true><<<GG, 256, 0, stream>>>(
        T16a, csr, offsets, dinv, T16b, ucol,         ucol + N,     N);
    k_gather<true, true><<<GG, 256, 0, stream>>>(
        T16b, csr, offsets, dinv, T16a, ucol + N,     ucol + 2 * N, N);
    k_gather<true, true><<<GG, 256, 0, stream>>>(
        T16a, csr, offsets, dinv, T16b, ucol + 2 * N, ucol + 3 * N, N);
    k_gather_mm<<<GG, 256, 0, stream>>>(
        T16b, csr, offsets, dinv, Wpack, out, ucol, cmat, N);
}